// Round 9
// baseline (484.465 us; speedup 1.0000x reference)
//
#include <hip/hip_runtime.h>
#include <math.h>

#define Bn 2
#define Sn 2048
#define En 2048
#define Hn 16
#define HDn 128

typedef __attribute__((ext_vector_type(8))) short short8;
typedef __attribute__((ext_vector_type(4))) float f32x4;
typedef unsigned short u16;
typedef unsigned int u32;

__device__ __forceinline__ float bf2f(u16 x){
  union { u32 u; float f; } v; v.u = ((u32)x) << 16; return v.f;
}
__device__ __forceinline__ u16 f2bf(float f){
  union { float f; u32 u; } v; v.f = f;
  u32 r = v.u + 0x7fff + ((v.u >> 16) & 1);
  return (u16)(r >> 16);
}
__device__ __forceinline__ void gload16(const u16* g, u16* l){
  __builtin_amdgcn_global_load_lds((const __attribute__((address_space(1))) void*)g,
                                   (__attribute__((address_space(3))) void*)l, 16, 0, 0);
}

// ------------- dtype detector: flag=1 if inputs are fp32, 0 if bf16 -------------
__global__ void detect_dtype(const u16* __restrict__ x, int* __restrict__ flag){
  int lane = threadIdx.x;
  int cnt = 0;
  #pragma unroll
  for (int i = 0; i < 4; i++){
    u16 u = x[lane*4 + i];
    int e = (u >> 7) & 0xFF;
    cnt += (e < 96 || e > 159) ? 1 : 0;
  }
  cnt += __shfl_xor(cnt, 1);  cnt += __shfl_xor(cnt, 2);  cnt += __shfl_xor(cnt, 4);
  cnt += __shfl_xor(cnt, 8);  cnt += __shfl_xor(cnt, 16); cnt += __shfl_xor(cnt, 32);
  if (lane == 0) flag[0] = (cnt > 32) ? 1 : 0;
}

// ------------- x -> bf16 workspace copy -------------
__global__ __launch_bounds__(256) void convert_x(const void* __restrict__ xin, u16* __restrict__ xb,
                                                 const int* __restrict__ flag){
  long i8 = ((long)blockIdx.x*256 + threadIdx.x)*8;
  if (flag[0]){
    const float* xf = (const float*)xin;
    float4 a = *(const float4*)(xf + i8);
    float4 b = *(const float4*)(xf + i8 + 4);
    u16 t[8] = {f2bf(a.x),f2bf(a.y),f2bf(a.z),f2bf(a.w),f2bf(b.x),f2bf(b.y),f2bf(b.z),f2bf(b.w)};
    *(uint4*)(xb + i8) = *(uint4*)t;
  } else {
    *(uint4*)(xb + i8) = *(const uint4*)((const u16*)xin + i8);
  }
}

// ------------- transpose 2048x2048 -> bf16: out[n][k] = (bf16)in[k][n] -------------
__device__ __forceinline__ void transpose_body(const void* __restrict__ in, u16* __restrict__ out,
                                               int blk, int f){
  __shared__ __align__(16) u16 t[64][72];
  int bx = blk & 31;
  int by = blk >> 5;
  int tid = threadIdx.x;
  #pragma unroll
  for (int c = tid; c < 512; c += 256){
    int r = c >> 3, col = (c & 7) << 3;
    long base = (long)((by<<6)+r)*2048 + (bx<<6) + col;
    u16 tmp[8];
    if (f){
      const float* pf = (const float*)in + base;
      float4 a = *(const float4*)pf;
      float4 b = *(const float4*)(pf + 4);
      tmp[0]=f2bf(a.x); tmp[1]=f2bf(a.y); tmp[2]=f2bf(a.z); tmp[3]=f2bf(a.w);
      tmp[4]=f2bf(b.x); tmp[5]=f2bf(b.y); tmp[6]=f2bf(b.z); tmp[7]=f2bf(b.w);
    } else {
      *(uint4*)tmp = *(const uint4*)((const u16*)in + base);
    }
    *(uint4*)&t[r][col] = *(uint4*)tmp;
  }
  __syncthreads();
  #pragma unroll
  for (int c = tid; c < 512; c += 256){
    int r = c >> 3, col = (c & 7) << 3;
    u16 tmp[8];
    #pragma unroll
    for (int i = 0; i < 8; i++) tmp[i] = t[col + i][r];
    *(uint4*)(out + (long)((bx<<6)+r)*2048 + (by<<6) + col) = *(uint4*)tmp;
  }
}

__global__ __launch_bounds__(256) void transpose2048(const void* __restrict__ in, u16* __restrict__ out,
                                                     const int* __restrict__ flag){
  transpose_body(in, out, blockIdx.x, flag[0]);
}

// fused prep: x->bf16 convert (blocks 0..4095) + nW weight transposes (1024 blocks each).
// Overlaps the two HBM-bound passes that previously ran serially on the stream.
__global__ __launch_bounds__(256) void prep_inputs(const void* __restrict__ x, u16* __restrict__ xb,
                const void* __restrict__ w0, const void* __restrict__ w1,
                const void* __restrict__ w2, const void* __restrict__ w3,
                const void* __restrict__ w4, u16* __restrict__ wt,
                const int* __restrict__ flag){
  int bi = blockIdx.x;
  if (bi < 4096){
    long i8 = ((long)bi*256 + threadIdx.x)*8;
    if (flag[0]){
      const float* xf = (const float*)x;
      float4 a = *(const float4*)(xf + i8);
      float4 b = *(const float4*)(xf + i8 + 4);
      u16 t[8] = {f2bf(a.x),f2bf(a.y),f2bf(a.z),f2bf(a.w),f2bf(b.x),f2bf(b.y),f2bf(b.z),f2bf(b.w)};
      *(uint4*)(xb + i8) = *(uint4*)t;
    } else {
      *(uint4*)(xb + i8) = *(const uint4*)((const u16*)x + i8);
    }
  } else {
    int wb = bi - 4096;
    int which = wb >> 10;
    const void* in = (which==0)?w0:(which==1)?w1:(which==2)?w2:(which==3)?w3:w4;
    transpose_body(in, wt + (size_t)which*((size_t)2048*2048), wb & 1023, flag[0]);
  }
}

// ------------- single GEMM: C = A @ Bt^T + bias; supertile swizzle -------------
// mode 0: plain, 1: *scale, 2: silu. outfp: write float C when flag==fp32.
// R9: f32 output path uses an LDS-chunked coalesced epilogue (4 x 16KB chunks of
// 128 rows x 32 f32 reusing the As/Bs LDS, granule-8 XOR swizzle keyed on row>>2)
// — kills the partial-line RMW the scalar store pattern caused (R3/R4 mechanism).
__global__ __launch_bounds__(256) void gemm_bt(const u16* __restrict__ A, const u16* __restrict__ Bt,
                const void* __restrict__ bias, void* __restrict__ C,
                int Mdim, int Ndim, int Kdim, int mode, float scale,
                const int* __restrict__ flag, int outfp){
  __shared__ __align__(16) u16 SM[2*128*32];   // As = SM, Bs = SM+4096 (16KB total)
  u16* As = SM;
  u16* Bs = SM + 128*32;
  int blk = blockIdx.x;
  int st = blk & 7, lid = blk >> 3;
  int m0 = ((st >> 1)*8 + (lid & 7)) << 7;
  int n0 = ((st & 1)*8 + (lid >> 3)) << 7;
  int tid = threadIdx.x;
  int w = tid >> 6, lane = tid & 63, l16 = lane & 15, quad = lane >> 4;
  int wm = w & 1, wn = w >> 1;
  int f = flag[0];
  int sr = lane >> 2;
  int sc = (lane & 3) << 3;
  const u16* gA = A  + (long)(m0 + (w<<5) + sr)*Kdim + sc;
  const u16* gB = Bt + (long)(n0 + (w<<5) + sr)*Kdim + sc;
  u16* lA0 = As + (w<<5)*32;  u16* lA1 = lA0 + 512;
  u16* lB0 = Bs + (w<<5)*32;  u16* lB1 = lB0 + 512;
  const long rowskip = (long)16*Kdim;

  f32x4 acc[4][4];
  #pragma unroll
  for (int i = 0; i < 4; i++)
    #pragma unroll
    for (int j = 0; j < 4; j++) acc[i][j] = (f32x4){0.f,0.f,0.f,0.f};

  for (int k0 = 0; k0 < Kdim; k0 += 32){
    __syncthreads();
    gload16(gA + k0,           lA0);
    gload16(gA + k0 + rowskip, lA1);
    gload16(gB + k0,           lB0);
    gload16(gB + k0 + rowskip, lB1);
    __syncthreads();
    short8 af[4], bfr[4];
    #pragma unroll
    for (int mf = 0; mf < 4; mf++) af[mf]  = *(const short8*)&As[(wm*64 + mf*16 + l16)*32 + quad*8];
    #pragma unroll
    for (int nf = 0; nf < 4; nf++) bfr[nf] = *(const short8*)&Bs[(wn*64 + nf*16 + l16)*32 + quad*8];
    #pragma unroll
    for (int mf = 0; mf < 4; mf++)
      #pragma unroll
      for (int nf = 0; nf < 4; nf++)
        acc[mf][nf] = __builtin_amdgcn_mfma_f32_16x16x32_bf16(af[mf], bfr[nf], acc[mf][nf], 0, 0, 0);
  }

  if (outfp && f){
    // ---- f32 LDS-chunked coalesced epilogue (full 128B lines out) ----
    float* LF = (float*)SM;                     // 4096 f32 = 128 rows x 32 cols
    #pragma unroll
    for (int c = 0; c < 4; c++){
      __syncthreads();
      if (wn == (c >> 1)){
        #pragma unroll
        for (int hh = 0; hh < 2; hh++){
          int nf = ((c & 1) << 1) + hh;
          int colc = ((nf & 1) << 4) + l16;     // 0..31 within chunk
          float bv = ((const float*)bias)[n0 + wn*64 + nf*16 + l16];
          #pragma unroll
          for (int mf = 0; mf < 4; mf++){
            #pragma unroll
            for (int r = 0; r < 4; r++){
              int row = wm*64 + mf*16 + quad*4 + r;
              float v = acc[mf][nf][r] + bv;
              if (mode == 1) v *= scale;
              else if (mode == 2) v = v / (1.0f + __expf(-v));
              LF[row*32 + (colc ^ (((row >> 2) & 3) << 3))] = v;
            }
          }
        }
      }
      __syncthreads();
      #pragma unroll
      for (int s = 0; s < 4; s++){
        int idx = tid*16 + s*4;
        int row = idx >> 5, cc = idx & 31;
        float4 vv = *(const float4*)&LF[row*32 + (cc ^ (((row >> 2) & 3) << 3))];
        *(float4*)&((float*)C)[(long)(m0 + row)*Ndim + n0 + (c << 5) + cc] = vv;
      }
    }
  } else {
    #pragma unroll
    for (int nf = 0; nf < 4; nf++){
      int col = n0 + wn*64 + nf*16 + l16;
      float bv = f ? ((const float*)bias)[col] : bf2f(((const u16*)bias)[col]);
      #pragma unroll
      for (int mf = 0; mf < 4; mf++){
        #pragma unroll
        for (int r = 0; r < 4; r++){
          int row = m0 + wm*64 + mf*16 + quad*4 + r;
          float v = acc[mf][nf][r] + bv;
          if (mode == 1) v *= scale;
          else if (mode == 2) v = v / (1.0f + __expf(-v));
          long idx = (long)row*Ndim + col;
          if (outfp && f) ((float*)C)[idx] = v;
          else            ((u16*)C)[idx] = f2bf(v);
        }
      }
    }
  }
}

// ------------- fused 4-weight GEMM, 256x256 tile, 8-phase pipeline (T1-T5) ------
// R7-verified schedule (143.7us, MfmaUtil 41%): even read distribution (<=8
// ds_reads/phase), b0 reads in P4/P8 tails after vmcnt(6)+barrier. KEPT FROZEN.
// REGISTER BUDGET (R5 lesson): 8 waves -> 256 regs/wave; acc=128 + operands ~120.
__global__ __launch_bounds__(512, 2) void gemm4_8ph(const u16* __restrict__ A, const u16* __restrict__ Wt4,
                const void* __restrict__ bq_, const void* __restrict__ bk_,
                const void* __restrict__ bv_, const void* __restrict__ bg_,
                u16* __restrict__ qo, u16* __restrict__ ko, u16* __restrict__ vo, u16* __restrict__ go,
                const int* __restrict__ flag, float qscale){
  __shared__ __align__(16) u16 LDS[65536];     // 128KB: As=LDS[0..32767], Bs=LDS[32768..65535]
  const size_t WE = (size_t)2048*2048;
  int blk = blockIdx.x;
  int xcd = blk & 7, lid = blk >> 3;            // 64 blocks per XCD
  int m0 = (((xcd << 1) | (lid & 1))) << 8;     // 2 m-tiles/XCD: A panel 2MB L2-resident
  int n0 = ((lid >> 1) & 7) << 8;
  int wsel = (lid >> 4) & 3;                    // 0:q 1:k 2:v 3:gate
  const u16* Bt = Wt4 + WE*(size_t)wsel;
  const void* bias = (wsel==0) ? bq_ : (wsel==1) ? bk_ : (wsel==2) ? bv_ : bg_;
  u16* Cout = (wsel==0) ? qo : (wsel==1) ? ko : (wsel==2) ? vo : go;
  int tid = threadIdx.x;
  int w = tid >> 6, lane = tid & 63, l16 = lane & 15, quad = lane >> 4;
  int wm = w >> 2, wn = w & 3;                  // wave tile: rows wm*128, cols wn*64
  int f = flag[0];

  int srowA = tid >> 3;                                            // 0..63
  int srowB = ((w >> 2) << 6) | ((w & 3) << 3) | ((tid >> 3) & 7); // {0-31, 64-95}
  int sg = ((tid & 7) ^ ((tid >> 3) & 7)) << 3;  // pre-swizzled source granule
  const u16* gA = A  + (long)(m0 + srowA)*2048 + sg;
  const u16* gB = Bt + (long)(n0 + srowB)*2048 + sg;
  u16* ldsA = LDS;
  u16* ldsB = LDS + 32768;
  const int wofsA = w << 9;
  const int wofsB = ((w >> 2) << 12) | ((w & 3) << 9);

  int g0 = quad ^ (l16 & 7);
  const int abase = (wm*128 + l16) * 64;
  const int bbase = (wn*64  + l16) * 64;

  f32x4 acc[8][4];
  #pragma unroll
  for (int i = 0; i < 8; i++)
    #pragma unroll
    for (int j = 0; j < 4; j++) acc[i][j] = (f32x4){0.f,0.f,0.f,0.f};
  short8 a[4][2], b0[2][2], b1[2][2];

#define STG_A(buf, tt, h) do{ \
  gload16(gA + (long)((h)*64)*2048       + (tt)*64, ldsA + (buf)*16384 + (h)*4096 + wofsA); \
  gload16(gA + (long)(128 + (h)*64)*2048 + (tt)*64, ldsA + (buf)*16384 + 8192 + (h)*4096 + wofsA); \
}while(0)
#define STG_B(buf, tt, h) do{ \
  gload16(gB + (long)((h)*32)*2048       + (tt)*64, ldsB + (buf)*16384 + (h)*2048 + wofsB); \
  gload16(gB + (long)(128 + (h)*32)*2048 + (tt)*64, ldsB + (buf)*16384 + 8192 + (h)*2048 + wofsB); \
}while(0)
#define LDA_Q(dst, buf, qm) do{ \
  _Pragma("unroll") for (int m_ = 0; m_ < 4; m_++) \
  _Pragma("unroll") for (int ks_ = 0; ks_ < 2; ks_++) \
    dst[m_][ks_] = *(const short8*)(ldsA + (buf)*16384 + abase + ((qm)*64 + m_*16)*64 + ((g0 ^ (ks_<<2))<<3)); \
}while(0)
#define LDB_Q(dst, buf, qn) do{ \
  _Pragma("unroll") for (int n_ = 0; n_ < 2; n_++) \
  _Pragma("unroll") for (int ks_ = 0; ks_ < 2; ks_++) \
    dst[n_][ks_] = *(const short8*)(ldsB + (buf)*16384 + bbase + (((qn)*2 + n_)*16)*64 + ((g0 ^ (ks_<<2))<<3)); \
}while(0)
#define MFMAQ(qm, qn, barr) do{ \
  _Pragma("unroll") for (int ks_ = 0; ks_ < 2; ks_++) \
  _Pragma("unroll") for (int m_ = 0; m_ < 4; m_++) \
  _Pragma("unroll") for (int n_ = 0; n_ < 2; n_++) \
    acc[(qm)*4 + m_][(qn)*2 + n_] = __builtin_amdgcn_mfma_f32_16x16x32_bf16( \
        a[m_][ks_], barr[n_][ks_], acc[(qm)*4 + m_][(qn)*2 + n_], 0, 0, 0); \
}while(0)
// POST (variadic) runs after the MFMA cluster, before the closing barrier.
#define PH_TAIL(qm, qn, barr, ...) do{ \
  asm volatile("" ::: "memory"); \
  __builtin_amdgcn_s_barrier(); \
  asm volatile("s_waitcnt lgkmcnt(0)" ::: "memory"); \
  __builtin_amdgcn_sched_barrier(0); \
  __builtin_amdgcn_s_setprio(1); \
  MFMAQ(qm, qn, barr); \
  __builtin_amdgcn_s_setprio(0); \
  __builtin_amdgcn_sched_barrier(0); \
  __VA_ARGS__; \
  asm volatile("" ::: "memory"); \
  __builtin_amdgcn_s_barrier(); \
}while(0)

  // prologue: tile0 {A0,B1,A1,B0} + tile1 {A0,B1,A1} = 7 half-tiles (14 loads).
  STG_A(0, 0, 0);
  STG_B(0, 0, 1);
  STG_A(0, 0, 1);
  STG_B(0, 0, 0);
  STG_A(1, 1, 0);
  STG_B(1, 1, 1);
  STG_A(1, 1, 1);
  asm volatile("s_waitcnt vmcnt(6)" ::: "memory");
  __builtin_amdgcn_s_barrier();
  LDB_Q(b0, 0, 0);   // tile0 B0 landed (first 8 loads); retires under P1's lgkmcnt(0)

  #pragma unroll 1
  for (int i = 0; i < 16; i++){
    const int t = i << 1;
    const bool full = (i < 15);
    // P1: read a(qm0) [8]; b0 was read in prologue / P8-prev tail
    LDA_Q(a, 0, 0);
    STG_B(1, t + 1, 0);
    PH_TAIL(0, 0, b0);
    // P2: read b1 [4]
    LDB_Q(b1, 0, 1);
    if (full) STG_A(0, t + 2, 0);
    PH_TAIL(0, 1, b1);
    // P3: read a(qm1) [8]
    LDA_Q(a, 0, 1);
    if (full) STG_B(0, t + 2, 1);
    PH_TAIL(1, 1, b1);
    // P4: post-MFMA read b0(buf1) — valid after all waves' vmcnt(6)+barrier1
    if (full){
      STG_A(0, t + 2, 1);
      asm volatile("s_waitcnt vmcnt(6)" ::: "memory");
    } else {
      asm volatile("s_waitcnt vmcnt(0)" ::: "memory");
    }
    PH_TAIL(1, 0, b0, LDB_Q(b0, 1, 0));
    // P5: read a(buf1,qm0) [8]; b0(buf1) from P4 tail
    LDA_Q(a, 1, 0);
    if (full) STG_B(0, t + 2, 0);
    PH_TAIL(0, 0, b0);
    // P6: read b1(buf1) [4]
    LDB_Q(b1, 1, 1);
    if (full) STG_A(1, t + 3, 0);
    PH_TAIL(0, 1, b1);
    // P7: read a(buf1,qm1) [8]
    LDA_Q(a, 1, 1);
    if (full) STG_B(1, t + 3, 1);
    PH_TAIL(1, 1, b1);
    // P8: post-MFMA read b0(buf0,next tile) — valid after vmcnt(6)+barrier1
    if (full){
      STG_A(1, t + 3, 1);
      asm volatile("s_waitcnt vmcnt(6)" ::: "memory");
      PH_TAIL(1, 0, b0, LDB_Q(b0, 0, 0));
    } else {
      PH_TAIL(1, 0, b0);
    }
  }

#undef STG_A
#undef STG_B
#undef LDA_Q
#undef LDB_Q
#undef MFMAQ
#undef PH_TAIL

  // ---- epilogue: acc -> LDS (256x256 u16) -> coalesced 16B/lane stores ----
  __syncthreads();
  #pragma unroll
  for (int nf = 0; nf < 4; nf++){
    int colL = wn*64 + nf*16 + l16;
    float bv = f ? ((const float*)bias)[n0 + colL] : bf2f(((const u16*)bias)[n0 + colL]);
    #pragma unroll
    for (int mf = 0; mf < 8; mf++){
      #pragma unroll
      for (int r = 0; r < 4; r++){
        int rowL = wm*128 + mf*16 + quad*4 + r;
        float v = acc[mf][nf][r] + bv;
        if (wsel == 0) v *= qscale;
        else if (wsel == 3) v = v / (1.0f + __expf(-v));
        LDS[rowL*256 + colL] = f2bf(v);
      }
    }
  }
  __syncthreads();
  #pragma unroll
  for (int it2 = 0; it2 < 16; it2++){
    int idx = it2*4096 + tid*8;
    int rowL = idx >> 8, colL = idx & 255;
    *(uint4*)(Cout + (long)(m0 + rowL)*2048 + n0 + colL) = *(const uint4*)(LDS + idx);
  }
}

// ------------- retention + scale + groupnorm + gate, QBLK=128 (R8, kept) -------------
__global__ __launch_bounds__(512) void retention(const u16* __restrict__ q, const u16* __restrict__ k,
     const u16* __restrict__ v, const u16* __restrict__ gate, const void* __restrict__ gnw,
     const void* __restrict__ gnb, const void* __restrict__ decay, u16* __restrict__ gated,
     const int* __restrict__ flag){
  __shared__ __align__(16) u16 Ks[64][136];
  __shared__ __align__(16) u16 Vt[128][72];
  __shared__ __align__(16) u16 Ss[8][16][72];
  int bh = blockIdx.x & 31;
  int it = 15 - (blockIdx.x >> 5);      // LPT: longest first (it=15 -> 32 j-tiles)
  int b = bh >> 4, h = bh & 15;
  int f = flag[0];
  float dec = f ? ((const float*)decay)[h] : bf2f(((const u16*)decay)[h]);
  int tid = threadIdx.x, w = tid >> 6, lane = tid & 63, l16 = lane & 15, quad = lane >> 4;

  float gw8[8], gb8[8];
  #pragma unroll
  for (int nf = 0; nf < 8; nf++){
    int ch = h*HDn + nf*16 + l16;
    gw8[nf] = f ? ((const float*)gnw)[ch] : bf2f(((const u16*)gnw)[ch]);
    gb8[nf] = f ? ((const float*)gnb)[ch] : bf2f(((const u16*)gnb)[ch]);
  }
  float ei4[4], ejl[4];
  #pragma unroll
  for (int r = 0; r < 4; r++) ei4[r] = __expf(dec * (float)(w*16 + quad*4 + r));
  #pragma unroll
  for (int nf = 0; nf < 4; nf++) ejl[nf] = __expf(-dec * (float)(nf*16 + l16));

  int i0 = it << 7;
  short8 qf[4];
  {
    int qrow = i0 + w*16 + l16;
    const u16* qbase = q + (long)(b*Sn + qrow)*En + h*HDn;
    #pragma unroll
    for (int kf = 0; kf < 4; kf++){
      uint4 t = *(const uint4*)(qbase + kf*32 + quad*8);
      qf[kf] = *(short8*)&t;
    }
  }
  f32x4 oacc[8];
  #pragma unroll
  for (int i = 0; i < 8; i++) oacc[i] = (f32x4){0.f,0.f,0.f,0.f};
  float rs[4] = {0.f,0.f,0.f,0.f};

  int njt = 2*it + 2;
  uint4 kreg[2], vreg[2];
  #pragma unroll
  for (int t = 0; t < 2; t++){
    int c = tid + t*512;
    int jr = c >> 4, dc = (c & 15) << 3;
    kreg[t] = *(const uint4*)(k + (long)(b*Sn + jr)*En + h*HDn + dc);
    int jr2 = c & 63, dc2 = (c >> 6) << 3;
    vreg[t] = *(const uint4*)(v + (long)(b*Sn + jr2)*En + h*HDn + dc2);
  }

  for (int jt = 0; jt < njt; jt++){
    int j0 = jt << 6;
    float etile = __expf(dec * (float)(i0 - j0));
    float em[4];
    #pragma unroll
    for (int r = 0; r < 4; r++) em[r] = etile * ei4[r];
    __syncthreads();
    #pragma unroll
    for (int t = 0; t < 2; t++){
      int c = tid + t*512;
      int jr = c >> 4, dc = (c & 15) << 3;
      *(uint4*)&Ks[jr][dc] = kreg[t];
      int jr2 = c & 63, dc2 = (c >> 6) << 3;
      u16 tmp[8]; *(uint4*)tmp = vreg[t];
      #pragma unroll
      for (int i = 0; i < 8; i++) Vt[dc2 + i][jr2] = tmp[i];
    }
    __syncthreads();
    if (jt + 1 < njt){
      int jn = j0 + 64;
      #pragma unroll
      for (int t = 0; t < 2; t++){
        int c = tid + t*512;
        int jr = c >> 4, dc = (c & 15) << 3;
        kreg[t] = *(const uint4*)(k + (long)(b*Sn + jn + jr)*En + h*HDn + dc);
        int jr2 = c & 63, dc2 = (c >> 6) << 3;
        vreg[t] = *(const uint4*)(v + (long)(b*Sn + jn + jr2)*En + h*HDn + dc2);
      }
    }
    #pragma unroll
    for (int nf = 0; nf < 4; nf++){
      f32x4 s = (f32x4){0.f,0.f,0.f,0.f};
      #pragma unroll
      for (int kf = 0; kf < 4; kf++){
        short8 kfr = *(const short8*)&Ks[nf*16 + l16][kf*32 + quad*8];
        s = __builtin_amdgcn_mfma_f32_16x16x32_bf16(qf[kf], kfr, s, 0, 0, 0);
      }
      int j = j0 + nf*16 + l16;
      #pragma unroll
      for (int r = 0; r < 4; r++){
        int i = i0 + w*16 + quad*4 + r;
        float p = s[r] * em[r] * ejl[nf];
        p = (i >= j) ? p : 0.0f;
        rs[r] += p;
        Ss[w][quad*4 + r][nf*16 + l16] = f2bf(p);
      }
    }
    asm volatile("" ::: "memory");
    __builtin_amdgcn_s_waitcnt(0xC07F);   // lgkmcnt(0), keeps vmcnt prefetch alive
    asm volatile("" ::: "memory");
    #pragma unroll
    for (int kf = 0; kf < 2; kf++){
      short8 pa = *(const short8*)&Ss[w][l16][kf*32 + quad*8];
      #pragma unroll
      for (int nf = 0; nf < 8; nf++){
        short8 vf = *(const short8*)&Vt[nf*16 + l16][kf*32 + quad*8];
        oacc[nf] = __builtin_amdgcn_mfma_f32_16x16x32_bf16(pa, vf, oacc[nf], 0, 0, 0);
      }
    }
  }
  #pragma unroll
  for (int r = 0; r < 4; r++){
    float x = rs[r];
    x += __shfl_xor(x, 1); x += __shfl_xor(x, 2); x += __shfl_xor(x, 4); x += __shfl_xor(x, 8);
    float sc = 1.0f / fmaxf(fabsf(x), 1.0f);
    #pragma unroll
    for (int nf = 0; nf < 8; nf++) oacc[nf][r] *= sc;
  }
  float mu[4], rstd[4];
  #pragma unroll
  for (int r = 0; r < 4; r++){
    float s1 = 0.f, s2 = 0.f;
    #pragma unroll
    for (int nf = 0; nf < 8; nf++){ float xv = oacc[nf][r]; s1 += xv; s2 += xv*xv; }
    s1 += __shfl_xor(s1, 1); s1 += __shfl_xor(s1, 2); s1 += __shfl_xor(s1, 4); s1 += __shfl_xor(s1, 8);
    s2 += __shfl_xor(s2, 1); s2 += __shfl_xor(s2, 2); s2 += __shfl_xor(s2, 4); s2 += __shfl_xor(s2, 8);
    float m = s1 * (1.0f/128.0f);
    float var = s2 * (1.0f/128.0f) - m*m;
    mu[r] = m; rstd[r] = rsqrtf(fmaxf(var, 0.0f) + 1e-5f);
  }
  #pragma unroll
  for (int nf = 0; nf < 8; nf++){
    int ch = h*HDn + nf*16 + l16;
    #pragma unroll
    for (int r = 0; r < 4; r++){
      int row = i0 + w*16 + quad*4 + r;
      long ga = (long)(b*Sn + row)*En + ch;
      float g = (oacc[nf][r] - mu[r]) * rstd[r] * gw8[nf] + gb8[nf];
      float gt = bf2f(gate[ga]);
      gated[ga] = f2bf(gt * g);
    }
  }
}

extern "C" void kernel_launch(void* const* d_in, const int* in_sizes, int n_in,
                              void* d_out, int out_size, void* d_ws, size_t ws_size,
                              hipStream_t stream){
  const void* x   = d_in[0];
  const void* Wq  = d_in[1];
  const void* bq  = d_in[2];
  const void* Wk  = d_in[3];
  const void* bk  = d_in[4];
  const void* Wv  = d_in[5];
  const void* bv  = d_in[6];
  const void* Wg  = d_in[7];
  const void* bg  = d_in[8];
  const void* Wo  = d_in[9];
  const void* bo  = d_in[10];
  const void* gnw = d_in[11];
  const void* gnb = d_in[12];
  const void* dec = d_in[13];

  u16* base = (u16*)d_ws;
  const size_t WE = (size_t)2048*2048;
  const size_t AE = (size_t)4096*2048;
  const float qscale = 0.08838834764831845f; // 128^-0.5
  u16* gatebuf = (u16*)d_out;   // gate scratch inside d_out until final GEMM overwrites

  const size_t fused_bytes  = (AE*4 + WE*4)*2 + 64;   // xb + 4*Wt + q/k/v
  const size_t fused5_bytes = (AE*4 + WE*5)*2 + 64;   // + Wo^T slot

  if (ws_size >= fused_bytes){
    // ---- fused path: all 4 input GEMMs in one 8-phase dispatch ----
    int five = (ws_size >= fused5_bytes) ? 1 : 0;
    u16* xb  = base;
    u16* Wt  = xb + AE;                       // 4 or 5 transposed weights
    u16* qb  = Wt + (five ? 5 : 4)*WE;
    u16* kb  = qb + AE;
    u16* vb  = kb + AE;
    int* flag = (int*)(vb + AE);
    u16* gtd = qb;

    detect_dtype<<<1, 64, 0, stream>>>((const u16*)x, flag);
    if (five){
      prep_inputs<<<4096 + 5120, 256, 0, stream>>>(x, xb, Wq, Wk, Wv, Wg, Wo, Wt, flag);
    } else {
      prep_inputs<<<4096 + 4096, 256, 0, stream>>>(x, xb, Wq, Wk, Wv, Wg, Wg, Wt, flag);
    }

    gemm4_8ph<<<512, 512, 0, stream>>>(xb, Wt, bq, bk, bv, bg, qb, kb, vb, gatebuf, flag, qscale);

    retention<<<512, 512, 0, stream>>>(qb, kb, vb, gatebuf, gnw, gnb, dec, gtd, flag);

    if (five){
      gemm_bt<<<512, 256, 0, stream>>>(gtd, Wt + 4*WE, bo, d_out, 4096, 2048, 2048, 0, 1.0f, flag, 1);
    } else {
      transpose2048<<<1024, 256, 0, stream>>>(Wo, Wt, flag);
      gemm_bt<<<512, 256, 0, stream>>>(gtd, Wt, bo, d_out, 4096, 2048, 2048, 0, 1.0f, flag, 1);
    }
  } else {
    // ---- serial fallback (R4 pipeline) ----
    u16* xb = base;
    u16* Wt = xb + AE;
    u16* qb = Wt + WE;
    u16* kb = qb + AE;
    u16* vb = kb + AE;
    int* flag = (int*)(vb + AE);
    u16* gtd = qb;

    detect_dtype<<<1, 64, 0, stream>>>((const u16*)x, flag);
    convert_x<<<4096, 256, 0, stream>>>(x, xb, flag);

    transpose2048<<<1024, 256, 0, stream>>>(Wq, Wt, flag);
    gemm_bt<<<512, 256, 0, stream>>>(xb, Wt, bq, qb, 4096, 2048, 2048, 1, qscale, flag, 0);
    transpose2048<<<1024, 256, 0, stream>>>(Wk, Wt, flag);
    gemm_bt<<<512, 256, 0, stream>>>(xb, Wt, bk, kb, 4096, 2048, 2048, 0, 1.0f, flag, 0);
    transpose2048<<<1024, 256, 0, stream>>>(Wv, Wt, flag);
    gemm_bt<<<512, 256, 0, stream>>>(xb, Wt, bv, vb, 4096, 2048, 2048, 0, 1.0f, flag, 0);
    transpose2048<<<1024, 256, 0, stream>>>(Wg, Wt, flag);
    gemm_bt<<<512, 256, 0, stream>>>(xb, Wt, bg, gatebuf, 4096, 2048, 2048, 2, 1.0f, flag, 0);

    retention<<<512, 512, 0, stream>>>(qb, kb, vb, gatebuf, gnw, gnb, dec, gtd, flag);

    transpose2048<<<1024, 256, 0, stream>>>(Wo, Wt, flag);
    gemm_bt<<<512, 256, 0, stream>>>(gtd, Wt, bo, d_out, 4096, 2048, 2048, 0, 1.0f, flag, 1);
  }
}

// Round 10
// 464.824 us; speedup vs baseline: 1.0423x; 1.0423x over previous
//
#include <hip/hip_runtime.h>
#include <math.h>

#define Bn 2
#define Sn 2048
#define En 2048
#define Hn 16
#define HDn 128

typedef __attribute__((ext_vector_type(8))) short short8;
typedef __attribute__((ext_vector_type(4))) float f32x4;
typedef unsigned short u16;
typedef unsigned int u32;

__device__ __forceinline__ float bf2f(u16 x){
  union { u32 u; float f; } v; v.u = ((u32)x) << 16; return v.f;
}
__device__ __forceinline__ u16 f2bf(float f){
  union { float f; u32 u; } v; v.f = f;
  u32 r = v.u + 0x7fff + ((v.u >> 16) & 1);
  return (u16)(r >> 16);
}
__device__ __forceinline__ void gload16(const u16* g, u16* l){
  __builtin_amdgcn_global_load_lds((const __attribute__((address_space(1))) void*)g,
                                   (__attribute__((address_space(3))) void*)l, 16, 0, 0);
}

// ------------- dtype detector: flag=1 if inputs are fp32, 0 if bf16 -------------
__global__ void detect_dtype(const u16* __restrict__ x, int* __restrict__ flag){
  int lane = threadIdx.x;
  int cnt = 0;
  #pragma unroll
  for (int i = 0; i < 4; i++){
    u16 u = x[lane*4 + i];
    int e = (u >> 7) & 0xFF;
    cnt += (e < 96 || e > 159) ? 1 : 0;
  }
  cnt += __shfl_xor(cnt, 1);  cnt += __shfl_xor(cnt, 2);  cnt += __shfl_xor(cnt, 4);
  cnt += __shfl_xor(cnt, 8);  cnt += __shfl_xor(cnt, 16); cnt += __shfl_xor(cnt, 32);
  if (lane == 0) flag[0] = (cnt > 32) ? 1 : 0;
}

// ------------- x -> bf16 workspace copy -------------
__global__ __launch_bounds__(256) void convert_x(const void* __restrict__ xin, u16* __restrict__ xb,
                                                 const int* __restrict__ flag){
  long i8 = ((long)blockIdx.x*256 + threadIdx.x)*8;
  if (flag[0]){
    const float* xf = (const float*)xin;
    float4 a = *(const float4*)(xf + i8);
    float4 b = *(const float4*)(xf + i8 + 4);
    u16 t[8] = {f2bf(a.x),f2bf(a.y),f2bf(a.z),f2bf(a.w),f2bf(b.x),f2bf(b.y),f2bf(b.z),f2bf(b.w)};
    *(uint4*)(xb + i8) = *(uint4*)t;
  } else {
    *(uint4*)(xb + i8) = *(const uint4*)((const u16*)xin + i8);
  }
}

// ------------- transpose 2048x2048 -> bf16: out[n][k] = (bf16)in[k][n] -------------
__device__ __forceinline__ void transpose_body(const void* __restrict__ in, u16* __restrict__ out,
                                               int blk, int f){
  __shared__ __align__(16) u16 t[64][72];
  int bx = blk & 31;
  int by = blk >> 5;
  int tid = threadIdx.x;
  #pragma unroll
  for (int c = tid; c < 512; c += 256){
    int r = c >> 3, col = (c & 7) << 3;
    long base = (long)((by<<6)+r)*2048 + (bx<<6) + col;
    u16 tmp[8];
    if (f){
      const float* pf = (const float*)in + base;
      float4 a = *(const float4*)pf;
      float4 b = *(const float4*)(pf + 4);
      tmp[0]=f2bf(a.x); tmp[1]=f2bf(a.y); tmp[2]=f2bf(a.z); tmp[3]=f2bf(a.w);
      tmp[4]=f2bf(b.x); tmp[5]=f2bf(b.y); tmp[6]=f2bf(b.z); tmp[7]=f2bf(b.w);
    } else {
      *(uint4*)tmp = *(const uint4*)((const u16*)in + base);
    }
    *(uint4*)&t[r][col] = *(uint4*)tmp;
  }
  __syncthreads();
  #pragma unroll
  for (int c = tid; c < 512; c += 256){
    int r = c >> 3, col = (c & 7) << 3;
    u16 tmp[8];
    #pragma unroll
    for (int i = 0; i < 8; i++) tmp[i] = t[col + i][r];
    *(uint4*)(out + (long)((bx<<6)+r)*2048 + (by<<6) + col) = *(uint4*)tmp;
  }
}

__global__ __launch_bounds__(256) void transpose2048(const void* __restrict__ in, u16* __restrict__ out,
                                                     const int* __restrict__ flag){
  transpose_body(in, out, blockIdx.x, flag[0]);
}

// fused: transpose 4 weight matrices in one dispatch (grid 4096)
__global__ __launch_bounds__(256) void transpose4(const void* __restrict__ in0, const void* __restrict__ in1,
                const void* __restrict__ in2, const void* __restrict__ in3,
                u16* __restrict__ out, const int* __restrict__ flag){
  int which = blockIdx.x >> 10;
  const void* in = (which==0)?in0:(which==1)?in1:(which==2)?in2:in3;
  u16* o = out + (size_t)which*((size_t)2048*2048);
  transpose_body(in, o, blockIdx.x & 1023, flag[0]);
}

// fused: transpose 5 weight matrices (q,k,v,g,o) in one dispatch (grid 5120)
__global__ __launch_bounds__(256) void transpose5(const void* __restrict__ in0, const void* __restrict__ in1,
                const void* __restrict__ in2, const void* __restrict__ in3, const void* __restrict__ in4,
                u16* __restrict__ out, const int* __restrict__ flag){
  int which = blockIdx.x >> 10;
  const void* in = (which==0)?in0:(which==1)?in1:(which==2)?in2:(which==3)?in3:in4;
  u16* o = out + (size_t)which*((size_t)2048*2048);
  transpose_body(in, o, blockIdx.x & 1023, flag[0]);
}

// ------------- single GEMM: C = A @ Bt^T + bias; supertile swizzle -------------
// mode 0: plain, 1: *scale, 2: silu. outfp: write float C when flag==fp32.
// NOTE (R9 lesson): the f32 scalar epilogue stores 64B sector-aligned segments
// (16 lanes x 4B contiguous) — NO RMW amplification. Do not "fix" it again.
__global__ __launch_bounds__(256) void gemm_bt(const u16* __restrict__ A, const u16* __restrict__ Bt,
                const void* __restrict__ bias, void* __restrict__ C,
                int Mdim, int Ndim, int Kdim, int mode, float scale,
                const int* __restrict__ flag, int outfp){
  __shared__ __align__(16) u16 As[128*32];
  __shared__ __align__(16) u16 Bs[128*32];
  int blk = blockIdx.x;
  int st = blk & 7, lid = blk >> 3;
  int m0 = ((st >> 1)*8 + (lid & 7)) << 7;
  int n0 = ((st & 1)*8 + (lid >> 3)) << 7;
  int tid = threadIdx.x;
  int w = tid >> 6, lane = tid & 63, l16 = lane & 15, quad = lane >> 4;
  int wm = w & 1, wn = w >> 1;
  int f = flag[0];
  int sr = lane >> 2;
  int sc = (lane & 3) << 3;
  const u16* gA = A  + (long)(m0 + (w<<5) + sr)*Kdim + sc;
  const u16* gB = Bt + (long)(n0 + (w<<5) + sr)*Kdim + sc;
  u16* lA0 = As + (w<<5)*32;  u16* lA1 = lA0 + 512;
  u16* lB0 = Bs + (w<<5)*32;  u16* lB1 = lB0 + 512;
  const long rowskip = (long)16*Kdim;

  f32x4 acc[4][4];
  #pragma unroll
  for (int i = 0; i < 4; i++)
    #pragma unroll
    for (int j = 0; j < 4; j++) acc[i][j] = (f32x4){0.f,0.f,0.f,0.f};

  for (int k0 = 0; k0 < Kdim; k0 += 32){
    __syncthreads();
    gload16(gA + k0,           lA0);
    gload16(gA + k0 + rowskip, lA1);
    gload16(gB + k0,           lB0);
    gload16(gB + k0 + rowskip, lB1);
    __syncthreads();
    short8 af[4], bfr[4];
    #pragma unroll
    for (int mf = 0; mf < 4; mf++) af[mf]  = *(const short8*)&As[(wm*64 + mf*16 + l16)*32 + quad*8];
    #pragma unroll
    for (int nf = 0; nf < 4; nf++) bfr[nf] = *(const short8*)&Bs[(wn*64 + nf*16 + l16)*32 + quad*8];
    #pragma unroll
    for (int mf = 0; mf < 4; mf++)
      #pragma unroll
      for (int nf = 0; nf < 4; nf++)
        acc[mf][nf] = __builtin_amdgcn_mfma_f32_16x16x32_bf16(af[mf], bfr[nf], acc[mf][nf], 0, 0, 0);
  }
  #pragma unroll
  for (int nf = 0; nf < 4; nf++){
    int col = n0 + wn*64 + nf*16 + l16;
    float bv = f ? ((const float*)bias)[col] : bf2f(((const u16*)bias)[col]);
    #pragma unroll
    for (int mf = 0; mf < 4; mf++){
      #pragma unroll
      for (int r = 0; r < 4; r++){
        int row = m0 + wm*64 + mf*16 + quad*4 + r;
        float v = acc[mf][nf][r] + bv;
        if (mode == 1) v *= scale;
        else if (mode == 2) v = v / (1.0f + __expf(-v));
        long idx = (long)row*Ndim + col;
        if (outfp && f) ((float*)C)[idx] = v;
        else            ((u16*)C)[idx] = f2bf(v);
      }
    }
  }
}

// ------------- fused 4-weight GEMM, 256x256 tile, 8-phase pipeline (T1-T5) ------
// R7-verified schedule (143.7us, MfmaUtil 41%): even read distribution (<=8
// ds_reads/phase), b0 reads in P4/P8 tails after vmcnt(6)+barrier. FROZEN.
// REGISTER BUDGET (R5 lesson): 8 waves -> 256 regs/wave; acc=128 + operands ~120.
__global__ __launch_bounds__(512, 2) void gemm4_8ph(const u16* __restrict__ A, const u16* __restrict__ Wt4,
                const void* __restrict__ bq_, const void* __restrict__ bk_,
                const void* __restrict__ bv_, const void* __restrict__ bg_,
                u16* __restrict__ qo, u16* __restrict__ ko, u16* __restrict__ vo, u16* __restrict__ go,
                const int* __restrict__ flag, float qscale){
  __shared__ __align__(16) u16 LDS[65536];     // 128KB: As=LDS[0..32767], Bs=LDS[32768..65535]
  const size_t WE = (size_t)2048*2048;
  int blk = blockIdx.x;
  int xcd = blk & 7, lid = blk >> 3;            // 64 blocks per XCD
  int m0 = (((xcd << 1) | (lid & 1))) << 8;     // 2 m-tiles/XCD: A panel 2MB L2-resident
  int n0 = ((lid >> 1) & 7) << 8;
  int wsel = (lid >> 4) & 3;                    // 0:q 1:k 2:v 3:gate
  const u16* Bt = Wt4 + WE*(size_t)wsel;
  const void* bias = (wsel==0) ? bq_ : (wsel==1) ? bk_ : (wsel==2) ? bv_ : bg_;
  u16* Cout = (wsel==0) ? qo : (wsel==1) ? ko : (wsel==2) ? vo : go;
  int tid = threadIdx.x;
  int w = tid >> 6, lane = tid & 63, l16 = lane & 15, quad = lane >> 4;
  int wm = w >> 2, wn = w & 3;                  // wave tile: rows wm*128, cols wn*64
  int f = flag[0];

  int srowA = tid >> 3;                                            // 0..63
  int srowB = ((w >> 2) << 6) | ((w & 3) << 3) | ((tid >> 3) & 7); // {0-31, 64-95}
  int sg = ((tid & 7) ^ ((tid >> 3) & 7)) << 3;  // pre-swizzled source granule
  const u16* gA = A  + (long)(m0 + srowA)*2048 + sg;
  const u16* gB = Bt + (long)(n0 + srowB)*2048 + sg;
  u16* ldsA = LDS;
  u16* ldsB = LDS + 32768;
  const int wofsA = w << 9;
  const int wofsB = ((w >> 2) << 12) | ((w & 3) << 9);

  int g0 = quad ^ (l16 & 7);
  const int abase = (wm*128 + l16) * 64;
  const int bbase = (wn*64  + l16) * 64;

  f32x4 acc[8][4];
  #pragma unroll
  for (int i = 0; i < 8; i++)
    #pragma unroll
    for (int j = 0; j < 4; j++) acc[i][j] = (f32x4){0.f,0.f,0.f,0.f};
  short8 a[4][2], b0[2][2], b1[2][2];

#define STG_A(buf, tt, h) do{ \
  gload16(gA + (long)((h)*64)*2048       + (tt)*64, ldsA + (buf)*16384 + (h)*4096 + wofsA); \
  gload16(gA + (long)(128 + (h)*64)*2048 + (tt)*64, ldsA + (buf)*16384 + 8192 + (h)*4096 + wofsA); \
}while(0)
#define STG_B(buf, tt, h) do{ \
  gload16(gB + (long)((h)*32)*2048       + (tt)*64, ldsB + (buf)*16384 + (h)*2048 + wofsB); \
  gload16(gB + (long)(128 + (h)*32)*2048 + (tt)*64, ldsB + (buf)*16384 + 8192 + (h)*2048 + wofsB); \
}while(0)
#define LDA_Q(dst, buf, qm) do{ \
  _Pragma("unroll") for (int m_ = 0; m_ < 4; m_++) \
  _Pragma("unroll") for (int ks_ = 0; ks_ < 2; ks_++) \
    dst[m_][ks_] = *(const short8*)(ldsA + (buf)*16384 + abase + ((qm)*64 + m_*16)*64 + ((g0 ^ (ks_<<2))<<3)); \
}while(0)
#define LDB_Q(dst, buf, qn) do{ \
  _Pragma("unroll") for (int n_ = 0; n_ < 2; n_++) \
  _Pragma("unroll") for (int ks_ = 0; ks_ < 2; ks_++) \
    dst[n_][ks_] = *(const short8*)(ldsB + (buf)*16384 + bbase + (((qn)*2 + n_)*16)*64 + ((g0 ^ (ks_<<2))<<3)); \
}while(0)
#define MFMAQ(qm, qn, barr) do{ \
  _Pragma("unroll") for (int ks_ = 0; ks_ < 2; ks_++) \
  _Pragma("unroll") for (int m_ = 0; m_ < 4; m_++) \
  _Pragma("unroll") for (int n_ = 0; n_ < 2; n_++) \
    acc[(qm)*4 + m_][(qn)*2 + n_] = __builtin_amdgcn_mfma_f32_16x16x32_bf16( \
        a[m_][ks_], barr[n_][ks_], acc[(qm)*4 + m_][(qn)*2 + n_], 0, 0, 0); \
}while(0)
// POST (variadic) runs after the MFMA cluster, before the closing barrier.
#define PH_TAIL(qm, qn, barr, ...) do{ \
  asm volatile("" ::: "memory"); \
  __builtin_amdgcn_s_barrier(); \
  asm volatile("s_waitcnt lgkmcnt(0)" ::: "memory"); \
  __builtin_amdgcn_sched_barrier(0); \
  __builtin_amdgcn_s_setprio(1); \
  MFMAQ(qm, qn, barr); \
  __builtin_amdgcn_s_setprio(0); \
  __builtin_amdgcn_sched_barrier(0); \
  __VA_ARGS__; \
  asm volatile("" ::: "memory"); \
  __builtin_amdgcn_s_barrier(); \
}while(0)

  // prologue: tile0 {A0,B1,A1,B0} + tile1 {A0,B1,A1} = 7 half-tiles (14 loads).
  STG_A(0, 0, 0);
  STG_B(0, 0, 1);
  STG_A(0, 0, 1);
  STG_B(0, 0, 0);
  STG_A(1, 1, 0);
  STG_B(1, 1, 1);
  STG_A(1, 1, 1);
  asm volatile("s_waitcnt vmcnt(6)" ::: "memory");
  __builtin_amdgcn_s_barrier();
  LDB_Q(b0, 0, 0);   // tile0 B0 landed (first 8 loads); retires under P1's lgkmcnt(0)

  #pragma unroll 1
  for (int i = 0; i < 16; i++){
    const int t = i << 1;
    const bool full = (i < 15);
    // P1: read a(qm0) [8]; b0 was read in prologue / P8-prev tail
    LDA_Q(a, 0, 0);
    STG_B(1, t + 1, 0);
    PH_TAIL(0, 0, b0);
    // P2: read b1 [4]
    LDB_Q(b1, 0, 1);
    if (full) STG_A(0, t + 2, 0);
    PH_TAIL(0, 1, b1);
    // P3: read a(qm1) [8]
    LDA_Q(a, 0, 1);
    if (full) STG_B(0, t + 2, 1);
    PH_TAIL(1, 1, b1);
    // P4: post-MFMA read b0(buf1) — valid after all waves' vmcnt(6)+barrier1
    if (full){
      STG_A(0, t + 2, 1);
      asm volatile("s_waitcnt vmcnt(6)" ::: "memory");
    } else {
      asm volatile("s_waitcnt vmcnt(0)" ::: "memory");
    }
    PH_TAIL(1, 0, b0, LDB_Q(b0, 1, 0));
    // P5: read a(buf1,qm0) [8]; b0(buf1) from P4 tail
    LDA_Q(a, 1, 0);
    if (full) STG_B(0, t + 2, 0);
    PH_TAIL(0, 0, b0);
    // P6: read b1(buf1) [4]
    LDB_Q(b1, 1, 1);
    if (full) STG_A(1, t + 3, 0);
    PH_TAIL(0, 1, b1);
    // P7: read a(buf1,qm1) [8]
    LDA_Q(a, 1, 1);
    if (full) STG_B(1, t + 3, 1);
    PH_TAIL(1, 1, b1);
    // P8: post-MFMA read b0(buf0,next tile) — valid after vmcnt(6)+barrier1
    if (full){
      STG_A(1, t + 3, 1);
      asm volatile("s_waitcnt vmcnt(6)" ::: "memory");
      PH_TAIL(1, 0, b0, LDB_Q(b0, 0, 0));
    } else {
      PH_TAIL(1, 0, b0);
    }
  }

#undef STG_A
#undef STG_B
#undef LDA_Q
#undef LDB_Q
#undef MFMAQ
#undef PH_TAIL

  // ---- epilogue: acc -> LDS (256x256 u16) -> coalesced 16B/lane stores ----
  __syncthreads();
  #pragma unroll
  for (int nf = 0; nf < 4; nf++){
    int colL = wn*64 + nf*16 + l16;
    float bv = f ? ((const float*)bias)[n0 + colL] : bf2f(((const u16*)bias)[n0 + colL]);
    #pragma unroll
    for (int mf = 0; mf < 8; mf++){
      #pragma unroll
      for (int r = 0; r < 4; r++){
        int rowL = wm*128 + mf*16 + quad*4 + r;
        float v = acc[mf][nf][r] + bv;
        if (wsel == 0) v *= qscale;
        else if (wsel == 3) v = v / (1.0f + __expf(-v));
        LDS[rowL*256 + colL] = f2bf(v);
      }
    }
  }
  __syncthreads();
  #pragma unroll
  for (int it2 = 0; it2 < 16; it2++){
    int idx = it2*4096 + tid*8;
    int rowL = idx >> 8, colL = idx & 255;
    *(uint4*)(Cout + (long)(m0 + rowL)*2048 + n0 + colL) = *(const uint4*)(LDS + idx);
  }
}

// ------------- retention + scale + groupnorm + gate, QBLK=128 (R8, kept) -------------
__global__ __launch_bounds__(512) void retention(const u16* __restrict__ q, const u16* __restrict__ k,
     const u16* __restrict__ v, const u16* __restrict__ gate, const void* __restrict__ gnw,
     const void* __restrict__ gnb, const void* __restrict__ decay, u16* __restrict__ gated,
     const int* __restrict__ flag){
  __shared__ __align__(16) u16 Ks[64][136];
  __shared__ __align__(16) u16 Vt[128][72];
  __shared__ __align__(16) u16 Ss[8][16][72];
  int bh = blockIdx.x & 31;
  int it = 15 - (blockIdx.x >> 5);      // LPT: longest first (it=15 -> 32 j-tiles)
  int b = bh >> 4, h = bh & 15;
  int f = flag[0];
  float dec = f ? ((const float*)decay)[h] : bf2f(((const u16*)decay)[h]);
  int tid = threadIdx.x, w = tid >> 6, lane = tid & 63, l16 = lane & 15, quad = lane >> 4;

  float gw8[8], gb8[8];
  #pragma unroll
  for (int nf = 0; nf < 8; nf++){
    int ch = h*HDn + nf*16 + l16;
    gw8[nf] = f ? ((const float*)gnw)[ch] : bf2f(((const u16*)gnw)[ch]);
    gb8[nf] = f ? ((const float*)gnb)[ch] : bf2f(((const u16*)gnb)[ch]);
  }
  float ei4[4], ejl[4];
  #pragma unroll
  for (int r = 0; r < 4; r++) ei4[r] = __expf(dec * (float)(w*16 + quad*4 + r));
  #pragma unroll
  for (int nf = 0; nf < 4; nf++) ejl[nf] = __expf(-dec * (float)(nf*16 + l16));

  int i0 = it << 7;
  short8 qf[4];
  {
    int qrow = i0 + w*16 + l16;
    const u16* qbase = q + (long)(b*Sn + qrow)*En + h*HDn;
    #pragma unroll
    for (int kf = 0; kf < 4; kf++){
      uint4 t = *(const uint4*)(qbase + kf*32 + quad*8);
      qf[kf] = *(short8*)&t;
    }
  }
  f32x4 oacc[8];
  #pragma unroll
  for (int i = 0; i < 8; i++) oacc[i] = (f32x4){0.f,0.f,0.f,0.f};
  float rs[4] = {0.f,0.f,0.f,0.f};

  int njt = 2*it + 2;
  uint4 kreg[2], vreg[2];
  #pragma unroll
  for (int t = 0; t < 2; t++){
    int c = tid + t*512;
    int jr = c >> 4, dc = (c & 15) << 3;
    kreg[t] = *(const uint4*)(k + (long)(b*Sn + jr)*En + h*HDn + dc);
    int jr2 = c & 63, dc2 = (c >> 6) << 3;
    vreg[t] = *(const uint4*)(v + (long)(b*Sn + jr2)*En + h*HDn + dc2);
  }

  for (int jt = 0; jt < njt; jt++){
    int j0 = jt << 6;
    float etile = __expf(dec * (float)(i0 - j0));
    float em[4];
    #pragma unroll
    for (int r = 0; r < 4; r++) em[r] = etile * ei4[r];
    __syncthreads();
    #pragma unroll
    for (int t = 0; t < 2; t++){
      int c = tid + t*512;
      int jr = c >> 4, dc = (c & 15) << 3;
      *(uint4*)&Ks[jr][dc] = kreg[t];
      int jr2 = c & 63, dc2 = (c >> 6) << 3;
      u16 tmp[8]; *(uint4*)tmp = vreg[t];
      #pragma unroll
      for (int i = 0; i < 8; i++) Vt[dc2 + i][jr2] = tmp[i];
    }
    __syncthreads();
    if (jt + 1 < njt){
      int jn = j0 + 64;
      #pragma unroll
      for (int t = 0; t < 2; t++){
        int c = tid + t*512;
        int jr = c >> 4, dc = (c & 15) << 3;
        kreg[t] = *(const uint4*)(k + (long)(b*Sn + jn + jr)*En + h*HDn + dc);
        int jr2 = c & 63, dc2 = (c >> 6) << 3;
        vreg[t] = *(const uint4*)(v + (long)(b*Sn + jn + jr2)*En + h*HDn + dc2);
      }
    }
    #pragma unroll
    for (int nf = 0; nf < 4; nf++){
      f32x4 s = (f32x4){0.f,0.f,0.f,0.f};
      #pragma unroll
      for (int kf = 0; kf < 4; kf++){
        short8 kfr = *(const short8*)&Ks[nf*16 + l16][kf*32 + quad*8];
        s = __builtin_amdgcn_mfma_f32_16x16x32_bf16(qf[kf], kfr, s, 0, 0, 0);
      }
      int j = j0 + nf*16 + l16;
      #pragma unroll
      for (int r = 0; r < 4; r++){
        int i = i0 + w*16 + quad*4 + r;
        float p = s[r] * em[r] * ejl[nf];
        p = (i >= j) ? p : 0.0f;
        rs[r] += p;
        Ss[w][quad*4 + r][nf*16 + l16] = f2bf(p);
      }
    }
    asm volatile("" ::: "memory");
    __builtin_amdgcn_s_waitcnt(0xC07F);   // lgkmcnt(0), keeps vmcnt prefetch alive
    asm volatile("" ::: "memory");
    #pragma unroll
    for (int kf = 0; kf < 2; kf++){
      short8 pa = *(const short8*)&Ss[w][l16][kf*32 + quad*8];
      #pragma unroll
      for (int nf = 0; nf < 8; nf++){
        short8 vf = *(const short8*)&Vt[nf*16 + l16][kf*32 + quad*8];
        oacc[nf] = __builtin_amdgcn_mfma_f32_16x16x32_bf16(pa, vf, oacc[nf], 0, 0, 0);
      }
    }
  }
  #pragma unroll
  for (int r = 0; r < 4; r++){
    float x = rs[r];
    x += __shfl_xor(x, 1); x += __shfl_xor(x, 2); x += __shfl_xor(x, 4); x += __shfl_xor(x, 8);
    float sc = 1.0f / fmaxf(fabsf(x), 1.0f);
    #pragma unroll
    for (int nf = 0; nf < 8; nf++) oacc[nf][r] *= sc;
  }
  float mu[4], rstd[4];
  #pragma unroll
  for (int r = 0; r < 4; r++){
    float s1 = 0.f, s2 = 0.f;
    #pragma unroll
    for (int nf = 0; nf < 8; nf++){ float xv = oacc[nf][r]; s1 += xv; s2 += xv*xv; }
    s1 += __shfl_xor(s1, 1); s1 += __shfl_xor(s1, 2); s1 += __shfl_xor(s1, 4); s1 += __shfl_xor(s1, 8);
    s2 += __shfl_xor(s2, 1); s2 += __shfl_xor(s2, 2); s2 += __shfl_xor(s2, 4); s2 += __shfl_xor(s2, 8);
    float m = s1 * (1.0f/128.0f);
    float var = s2 * (1.0f/128.0f) - m*m;
    mu[r] = m; rstd[r] = rsqrtf(fmaxf(var, 0.0f) + 1e-5f);
  }
  #pragma unroll
  for (int nf = 0; nf < 8; nf++){
    int ch = h*HDn + nf*16 + l16;
    #pragma unroll
    for (int r = 0; r < 4; r++){
      int row = i0 + w*16 + quad*4 + r;
      long ga = (long)(b*Sn + row)*En + ch;
      float g = (oacc[nf][r] - mu[r]) * rstd[r] * gw8[nf] + gb8[nf];
      float gt = bf2f(gate[ga]);
      gated[ga] = f2bf(gt * g);
    }
  }
}

extern "C" void kernel_launch(void* const* d_in, const int* in_sizes, int n_in,
                              void* d_out, int out_size, void* d_ws, size_t ws_size,
                              hipStream_t stream){
  const void* x   = d_in[0];
  const void* Wq  = d_in[1];
  const void* bq  = d_in[2];
  const void* Wk  = d_in[3];
  const void* bk  = d_in[4];
  const void* Wv  = d_in[5];
  const void* bv  = d_in[6];
  const void* Wg  = d_in[7];
  const void* bg  = d_in[8];
  const void* Wo  = d_in[9];
  const void* bo  = d_in[10];
  const void* gnw = d_in[11];
  const void* gnb = d_in[12];
  const void* dec = d_in[13];

  u16* base = (u16*)d_ws;
  const size_t WE = (size_t)2048*2048;
  const size_t AE = (size_t)4096*2048;
  const float qscale = 0.08838834764831845f; // 128^-0.5
  u16* gatebuf = (u16*)d_out;   // gate scratch inside d_out until final GEMM overwrites

  const size_t fused_bytes  = (AE*4 + WE*4)*2 + 64;   // xb + 4*Wt + q/k/v
  const size_t fused5_bytes = (AE*4 + WE*5)*2 + 64;   // + Wo^T slot

  if (ws_size >= fused_bytes){
    // ---- fused path: all 4 input GEMMs in one 8-phase dispatch ----
    int five = (ws_size >= fused5_bytes) ? 1 : 0;
    u16* xb  = base;
    u16* Wt  = xb + AE;                       // 4 or 5 transposed weights
    u16* qb  = Wt + (five ? 5 : 4)*WE;
    u16* kb  = qb + AE;
    u16* vb  = kb + AE;
    int* flag = (int*)(vb + AE);
    u16* gtd = qb;

    detect_dtype<<<1, 64, 0, stream>>>((const u16*)x, flag);
    convert_x<<<4096, 256, 0, stream>>>(x, xb, flag);
    if (five) transpose5<<<5120, 256, 0, stream>>>(Wq, Wk, Wv, Wg, Wo, Wt, flag);
    else      transpose4<<<4096, 256, 0, stream>>>(Wq, Wk, Wv, Wg, Wt, flag);

    gemm4_8ph<<<512, 512, 0, stream>>>(xb, Wt, bq, bk, bv, bg, qb, kb, vb, gatebuf, flag, qscale);

    retention<<<512, 512, 0, stream>>>(qb, kb, vb, gatebuf, gnw, gnb, dec, gtd, flag);

    if (five){
      gemm_bt<<<512, 256, 0, stream>>>(gtd, Wt + 4*WE, bo, d_out, 4096, 2048, 2048, 0, 1.0f, flag, 1);
    } else {
      transpose2048<<<1024, 256, 0, stream>>>(Wo, Wt, flag);
      gemm_bt<<<512, 256, 0, stream>>>(gtd, Wt, bo, d_out, 4096, 2048, 2048, 0, 1.0f, flag, 1);
    }
  } else {
    // ---- serial fallback (R4 pipeline) ----
    u16* xb = base;
    u16* Wt = xb + AE;
    u16* qb = Wt + WE;
    u16* kb = qb + AE;
    u16* vb = kb + AE;
    int* flag = (int*)(vb + AE);
    u16* gtd = qb;

    detect_dtype<<<1, 64, 0, stream>>>((const u16*)x, flag);
    convert_x<<<4096, 256, 0, stream>>>(x, xb, flag);

    transpose2048<<<1024, 256, 0, stream>>>(Wq, Wt, flag);
    gemm_bt<<<512, 256, 0, stream>>>(xb, Wt, bq, qb, 4096, 2048, 2048, 1, qscale, flag, 0);
    transpose2048<<<1024, 256, 0, stream>>>(Wk, Wt, flag);
    gemm_bt<<<512, 256, 0, stream>>>(xb, Wt, bk, kb, 4096, 2048, 2048, 0, 1.0f, flag, 0);
    transpose2048<<<1024, 256, 0, stream>>>(Wv, Wt, flag);
    gemm_bt<<<512, 256, 0, stream>>>(xb, Wt, bv, vb, 4096, 2048, 2048, 0, 1.0f, flag, 0);
    transpose2048<<<1024, 256, 0, stream>>>(Wg, Wt, flag);
    gemm_bt<<<512, 256, 0, stream>>>(xb, Wt, bg, gatebuf, 4096, 2048, 2048, 2, 1.0f, flag, 0);

    retention<<<512, 512, 0, stream>>>(qb, kb, vb, gatebuf, gnw, gnb, dec, gtd, flag);

    transpose2048<<<1024, 256, 0, stream>>>(Wo, Wt, flag);
    gemm_bt<<<512, 256, 0, stream>>>(gtd, Wt, bo, d_out, 4096, 2048, 2048, 0, 1.0f, flag, 1);
  }
}